// Round 8
// baseline (286.748 us; speedup 1.0000x reference)
//
#include <hip/hip_runtime.h>
#include <hip/hip_fp16.h>

#define B_ 2
#define S_ 2048
#define D_ 2048
#define H_ 32
#define KV_ 8
#define HD_ 64

typedef unsigned short bf16_t;
typedef __attribute__((ext_vector_type(8))) short short8;
typedef __attribute__((ext_vector_type(4))) float floatx4;
typedef __attribute__((ext_vector_type(16))) float floatx16;

__device__ __forceinline__ bf16_t f2bf(float f) {
  union { float f; unsigned u; } c; c.f = f;
  unsigned u = c.u;
  u += 0x7fffu + ((u >> 16) & 1u);          // round-to-nearest-even
  return (bf16_t)(u >> 16);
}

__device__ __forceinline__ unsigned pk_bf16(float a, float b) {
#if __has_builtin(__builtin_amdgcn_cvt_pk_bf16_f32)
  auto v = __builtin_amdgcn_cvt_pk_bf16_f32(a, b);
  unsigned u; __builtin_memcpy(&u, &v, 4); return u;
#else
  return (unsigned)f2bf(a) | ((unsigned)f2bf(b) << 16);
#endif
}

__device__ __forceinline__ float fexp2(float x) {
#if __has_builtin(__builtin_amdgcn_exp2f)
  return __builtin_amdgcn_exp2f(x);
#else
  return exp2f(x);
#endif
}

__device__ __forceinline__ void load_lds16(const void* g, void* l) {
  __builtin_amdgcn_global_load_lds(
      (const __attribute__((address_space(1))) void*)g,
      (__attribute__((address_space(3))) void*)l, 16, 0, 0);
}

// ---------------- prep: fp32->bf16 casts + packed fp16 rope table ----------------
__device__ __forceinline__ void cvt4(const float* __restrict__ in,
                                     bf16_t* __restrict__ out, int i) {
  float4 v = ((const float4*)in)[i];
  ushort4 o;
  o.x = f2bf(v.x); o.y = f2bf(v.y); o.z = f2bf(v.z); o.w = f2bf(v.w);
  ((ushort4*)out)[i] = o;
}

__global__ __launch_bounds__(256) void prep(
    const float* __restrict__ x, bf16_t* __restrict__ xb,
    const float* __restrict__ wqkv, bf16_t* __restrict__ wqkvb,
    const float* __restrict__ wout, bf16_t* __restrict__ woutb,
    const float* __restrict__ cs, const float* __restrict__ sn,
    unsigned* __restrict__ tab) {
  const int bid = blockIdx.x;
  if (bid < 8192) {
    cvt4(x, xb, bid * 256 + threadIdx.x);
  } else if (bid < 14336) {
    cvt4(wqkv, wqkvb, (bid - 8192) * 256 + threadIdx.x);
  } else if (bid < 18432) {
    cvt4(wout, woutb, (bid - 14336) * 256 + threadIdx.x);
  } else {
    const int i = (bid - 18432) * 256 + threadIdx.x;   // 131072 entries
    __half2 h = __floats2half2_rn(cs[i], sn[i]);
    unsigned u; __builtin_memcpy(&u, &h, 4);
    tab[i] = u;
  }
}

// ---------------- bf16 GEMM: C[M,N] = A[M,K] * B^T (f32 out) ----------------
// BK=64 (half the barrier drains of BK=32), XOR-swizzled LDS:
// LDS[row][slot] = global[row][slot ^ (row&7)] (slot = 16B chunk, 8/row).
__global__ __launch_bounds__(256) void gemm_bt(
    const bf16_t* __restrict__ A, const bf16_t* __restrict__ Bm,
    float* __restrict__ C, int M, int N, int K) {
  __shared__ __attribute__((aligned(16))) bf16_t As[128 * 64];  // 16 KB
  __shared__ __attribute__((aligned(16))) bf16_t Bs[128 * 64];  // 16 KB
  const int tid = threadIdx.x;
  const int lane = tid & 63;
  const int wave = tid >> 6;
  const int bm = blockIdx.y * 128, bn = blockIdx.x * 128;
  const int wm = (wave >> 1) * 64, wn = (wave & 1) * 64;
  const int lr = lane & 15, quad = lane >> 4;

  floatx4 acc[4][4] = {};

  const bf16_t* Ab = A + (size_t)bm * K;
  const bf16_t* Bb = Bm + (size_t)bn * K;

  for (int k0 = 0; k0 < K; k0 += 64) {
    __syncthreads();
#pragma unroll
    for (int p = 0; p < 4; p++) {
      const int idx = p * 256 + tid;
      const int row = idx >> 3, sc = idx & 7;
      const int gc = sc ^ (row & 7);
      load_lds16(Ab + (size_t)row * K + k0 + gc * 8, &As[idx * 8]);
      load_lds16(Bb + (size_t)row * K + k0 + gc * 8, &Bs[idx * 8]);
    }
    __syncthreads();

#pragma unroll
    for (int ks = 0; ks < 2; ks++) {
      short8 af[4], bfr[4];
#pragma unroll
      for (int i = 0; i < 4; i++) {
        const int ra = wm + i * 16 + lr;
        const int rb = wn + i * 16 + lr;
        af[i]  = *(const short8*)&As[ra * 64 + (((ks * 4 + quad) ^ (ra & 7)) * 8)];
        bfr[i] = *(const short8*)&Bs[rb * 64 + (((ks * 4 + quad) ^ (rb & 7)) * 8)];
      }
#pragma unroll
      for (int mi = 0; mi < 4; mi++)
#pragma unroll
        for (int ni = 0; ni < 4; ni++)
          acc[mi][ni] = __builtin_amdgcn_mfma_f32_16x16x32_bf16(af[mi], bfr[ni], acc[mi][ni], 0, 0, 0);
    }
  }

#pragma unroll
  for (int mi = 0; mi < 4; mi++) {
    const int row = bm + wm + mi * 16 + quad * 4;
#pragma unroll
    for (int ni = 0; ni < 4; ni++) {
      const int col = bn + wn + ni * 16 + lr;
      float* cp = C + (size_t)row * N + col;
#pragma unroll
      for (int r = 0; r < 4; r++) cp[(size_t)r * N] = acc[mi][ni][r];
    }
  }
}

// ---------------- fused QKV GEMM + RoPE (fp16 table) + repack ----------------
// Ts transpose scratch aliases As/Bs (dead after the K-loop): LDS 32 KB
// => 4 blocks/CU. One uniform __syncthreads() after the K-loop.
__global__ __launch_bounds__(256, 4) void gemm_qkv(
    const bf16_t* __restrict__ A, const bf16_t* __restrict__ Bm,
    const unsigned* __restrict__ tab,
    bf16_t* __restrict__ q, bf16_t* __restrict__ k, bf16_t* __restrict__ vt) {
  const int K = 2048;
  __shared__ __attribute__((aligned(16))) bf16_t As[128 * 64];  // 16 KB
  __shared__ __attribute__((aligned(16))) bf16_t Bs[128 * 64];  // 16 KB
  const int tid = threadIdx.x;
  const int lane = tid & 63;
  const int wave = tid >> 6;
  const int bm = blockIdx.y * 128, bn = blockIdx.x * 128;
  const int wm = (wave >> 1) * 64, wn = (wave & 1) * 64;
  const int lr = lane & 15, quad = lane >> 4;

  floatx4 acc[4][4] = {};

  const bf16_t* Ab = A + (size_t)bm * K;
  const bf16_t* Bb = Bm + (size_t)bn * K;

  for (int k0 = 0; k0 < K; k0 += 64) {
    __syncthreads();
#pragma unroll
    for (int p = 0; p < 4; p++) {
      const int idx = p * 256 + tid;
      const int row = idx >> 3, sc = idx & 7;
      const int gc = sc ^ (row & 7);
      load_lds16(Ab + (size_t)row * K + k0 + gc * 8, &As[idx * 8]);
      load_lds16(Bb + (size_t)row * K + k0 + gc * 8, &Bs[idx * 8]);
    }
    __syncthreads();

#pragma unroll
    for (int ks = 0; ks < 2; ks++) {
      short8 af[4], bfr[4];
#pragma unroll
      for (int i = 0; i < 4; i++) {
        const int ra = wm + i * 16 + lr;
        const int rb = wn + i * 16 + lr;
        af[i]  = *(const short8*)&As[ra * 64 + (((ks * 4 + quad) ^ (ra & 7)) * 8)];
        bfr[i] = *(const short8*)&Bs[rb * 64 + (((ks * 4 + quad) ^ (rb & 7)) * 8)];
      }
#pragma unroll
      for (int mi = 0; mi < 4; mi++)
#pragma unroll
        for (int ni = 0; ni < 4; ni++)
          acc[mi][ni] = __builtin_amdgcn_mfma_f32_16x16x32_bf16(af[mi], bfr[ni], acc[mi][ni], 0, 0, 0);
    }
  }

  __syncthreads();   // uniform: As/Bs reads retired; safe to reuse as scratch

  const int f0 = bn + wn;              // wave-uniform feature base (multiple of 64)
  const int srow0 = bm + wm;
  const int bb = srow0 >> 11, s0 = srow0 & 2047;

  if (f0 < 2560) {                     // Q or K head: in-register rope
    const bool isq = (f0 < 2048);
    const float scale = isq ? 0.18033688011f : 1.0f;   // 0.125 * log2(e)
    bf16_t* dst = isq ? (q + (size_t)(bb * H_ + (f0 >> 6)) * S_ * HD_)
                      : (k + (size_t)(bb * KV_ + ((f0 - 2048) >> 6)) * S_ * HD_);
#pragma unroll
    for (int mi = 0; mi < 4; mi++) {
#pragma unroll
      for (int r = 0; r < 4; r++) {
        const int sr = s0 + mi * 16 + quad * 4 + r;
        const unsigned* tp = tab + (size_t)sr * HD_;
        bf16_t* drow = dst + (size_t)sr * HD_;
#pragma unroll
        for (int ni = 0; ni < 4; ni++) {
          const int d = ni * 16 + lr;
          const unsigned w = tp[d];
          __half2 h2; __builtin_memcpy(&h2, &w, 4);
          const float2 cf = __half22float2(h2);
          const float t = acc[mi][ni][r];
          const float oth = acc[mi][ni ^ 2][r];
          const float rot = (ni < 2) ? -oth : oth;   // d<32 iff ni<2
          drow[d] = f2bf((t * cf.x + rot * cf.y) * scale);
        }
      }
    }
  } else {                             // V head: 2-pass transpose via aliased scratch
    const int hv = (f0 - 2560) >> 6;
    // per-wave 4608 B region: waves 0-1 in As, waves 2-3 in Bs (16B-aligned)
    bf16_t* ts = (wave < 2) ? (As + wave * 2304) : (Bs + (wave - 2) * 2304);
    const int rl = lane >> 1, hf = lane & 1;
#pragma unroll
    for (int p = 0; p < 2; p++) {
#pragma unroll
      for (int nn = 0; nn < 2; nn++) {
        const int ni = 2 * p + nn;
#pragma unroll
        for (int mi = 0; mi < 4; mi++) {
          uint2 pw;
          pw.x = pk_bf16(acc[mi][ni][0], acc[mi][ni][1]);
          pw.y = pk_bf16(acc[mi][ni][2], acc[mi][ni][3]);
          *(uint2*)&ts[(nn * 16 + lr) * 72 + mi * 16 + quad * 4] = pw;
        }
      }
      // same-wave RAW/WAR: DS pipe is in-order per wave, compiler emits lgkmcnt
      bf16_t* vrow = vt + ((size_t)(bb * KV_ + hv) * HD_ + p * 32 + rl) * S_ + s0 + hf * 32;
#pragma unroll
      for (int j = 0; j < 4; j++)
        *(short8*)(vrow + j * 8) = *(const short8*)&ts[rl * 72 + hf * 32 + j * 8];
    }
  }
}

// ---------------- flash attention v8: staged 4-wave blocks, balanced assignment ----
// Block owns 128 q-rows (4 waves x 32); K/V staged into 32 KB LDS, double-buffered.
// Grid 1024 = 4 groups x 256. With bid->CU ~ RR (bid mod 256), each CU gets one
// block per group with Tb = {15-c, 11-c, 4+c, c} (c = (bid>>6)&3) => every CU
// receives exactly Sum(2Tb+2) = 68 k-tiles -> no per-CU imbalance tail.
// Heavy group (g=0) dispatches first (LPT fallback). Head XCD-grouped via bid&63.

__device__ __forceinline__ void stage64_4w(const bf16_t* __restrict__ gk,
                                           const bf16_t* __restrict__ gv,
                                           bf16_t* kbuf, bf16_t* vbuf, int tid) {
#pragma unroll
  for (int j = 0; j < 2; j++) {
    const int idx = j * 256 + tid;      // 512 chunks of 16B per 64x64 tile
    const int row = idx >> 3;
    const int sc  = idx & 7;
    const int gc  = sc ^ (row & 7);
    load_lds16(gk + (size_t)row * HD_ + gc * 8, kbuf + idx * 8);
    load_lds16(gv + (size_t)row * S_  + gc * 8, vbuf + idx * 8);
  }
}

// halves-exchange: x = [a.lo | b.lo], y = [a.hi | b.hi] (lanes 0-31 | 32-63)
__device__ __forceinline__ void hswap(unsigned a, unsigned b, unsigned& x, unsigned& y) {
#if __has_builtin(__builtin_amdgcn_permlane32_swap)
  auto r = __builtin_amdgcn_permlane32_swap(a, b, false, false);
  x = (unsigned)r[0]; y = (unsigned)r[1];
#else
  const unsigned pa = (unsigned)__shfl_xor((int)a, 32, 64);
  const unsigned pb = (unsigned)__shfl_xor((int)b, 32, 64);
  const bool hi = (threadIdx.x & 32) != 0;
  x = hi ? pb : a;
  y = hi ? b : pa;
#endif
}

// one k-subtile (32 k) of P in lane regs -> two PV B-fragments (k-slices of 16)
__device__ __forceinline__ void build_pfrag(const floatx16& p, short8& f0, short8& f1) {
  unsigned w[8];
  const unsigned c01 = pk_bf16(p[0], p[1]);
  const unsigned c45 = pk_bf16(p[4], p[5]);
  const unsigned c23 = pk_bf16(p[2], p[3]);
  const unsigned c67 = pk_bf16(p[6], p[7]);
  hswap(c01, c45, w[0], w[2]);
  hswap(c23, c67, w[1], w[3]);
  const unsigned d01 = pk_bf16(p[8], p[9]);
  const unsigned d45 = pk_bf16(p[12], p[13]);
  const unsigned d23 = pk_bf16(p[10], p[11]);
  const unsigned d67 = pk_bf16(p[14], p[15]);
  hswap(d01, d45, w[4], w[6]);
  hswap(d23, d67, w[5], w[7]);
  __builtin_memcpy(&f0, &w[0], 16);
  __builtin_memcpy(&f1, &w[4], 16);
}

__global__ __launch_bounds__(256, 2) void flash_attn(
    const bf16_t* __restrict__ Q,   // [B*H, S, 64] (pre-scaled by 0.125*log2e)
    const bf16_t* __restrict__ Kc,  // [B*KV, S, 64]
    const bf16_t* __restrict__ Vt,  // [B*KV, 64, S]
    bf16_t* __restrict__ O) {       // [B, S, H*64]
  __shared__ __attribute__((aligned(16))) bf16_t Ks[2 * 4096];  // 16 KB
  __shared__ __attribute__((aligned(16))) bf16_t Vs[2 * 4096];  // 16 KB -> 32 KB
  // balanced decode: bid = g*256 + j; head = XCD-grouped(j&63); c = (j>>6)&3;
  // Tb = {15-c, 11-c, 4+c, c}[g] -> per-CU k-tile total is uniform (68).
  const int bid = blockIdx.x;
  const int j = bid & 255;
  const int g = bid >> 8;
  const int c = (j >> 6) & 3;
  const int head = ((j & 7) << 3) | ((j >> 3) & 7);
  const int Tb = (g < 2) ? (15 - 4 * g - c) : (4 * (3 - g) + c);
  const int b = head >> 5, h = head & 31;
  const int kvh = b * KV_ + (h >> 2);
  const int tid = threadIdx.x;
  const int wave = tid >> 6, lane = tid & 63;
  const int cq = lane & 31, hh = lane >> 5;
  const int sw7 = lane & 7;
  const int q0 = Tb * 128 + wave * 32, qg = q0 + cq;
  const int nt = 2 * Tb + 2;            // 64-k tiles staged by the block
  const int last = 2 * Tb + (wave >> 1);  // this wave's diag tile

  const bf16_t* kb = Kc + (size_t)kvh * S_ * HD_;
  const bf16_t* vb = Vt + (size_t)kvh * HD_ * S_;

  // Q fragments (B operand): lane holds Q[q0+cq][ds*16 + hh*8 .. +8]
  const bf16_t* qp = Q + ((size_t)head * S_ + qg) * HD_ + hh * 8;
  short8 qf[4];
#pragma unroll
  for (int ds = 0; ds < 4; ds++) qf[ds] = *(const short8*)(qp + ds * 16);

  floatx16 o0 = {}, o1 = {};
  float m = -1e30f, l = 0.f;            // l kept per-half; merged at store

  stage64_4w(kb, vb, Ks, Vs, tid);

  for (int kt = 0; kt < nt; kt++) {
    __syncthreads();
    if (kt + 1 < nt)
      stage64_4w(kb + (size_t)(kt + 1) * 64 * HD_, vb + (kt + 1) * 64,
                 Ks + ((kt + 1) & 1) * 4096, Vs + ((kt + 1) & 1) * 4096, tid);
    if (kt > last) continue;            // wave-uniform; barriers still honored
    const bf16_t* Kt = Ks + (kt & 1) * 4096;
    const bf16_t* Vc = Vs + (kt & 1) * 4096;

    // QK^T: S^T[k][q], two 32-k subtiles, K summed over 4 d-slices
    floatx16 s0 = {}, s1 = {};
    __builtin_amdgcn_s_setprio(1);
#pragma unroll
    for (int ds = 0; ds < 4; ds++) {
      const int slot = (((ds * 2 + hh) ^ sw7) * 8);
      const short8 k0 = *(const short8*)&Kt[cq * 64 + slot];
      const short8 k1 = *(const short8*)&Kt[(32 + cq) * 64 + slot];
      s0 = __builtin_amdgcn_mfma_f32_32x32x16_bf16(k0, qf[ds], s0, 0, 0, 0);
      s1 = __builtin_amdgcn_mfma_f32_32x32x16_bf16(k1, qf[ds], s1, 0, 0, 0);
    }
    __builtin_amdgcn_s_setprio(0);

    // causal mask on this wave's diag tile
    if (kt == last) {
      const int kbase = kt * 64 + 4 * hh;
#pragma unroll
      for (int r = 0; r < 16; r++) {
        const int kg = kbase + (r & 3) + 8 * (r >> 2);
        s0[r] = (kg <= qg) ? s0[r] : -1e30f;
        s1[r] = (kg + 32 <= qg) ? s1[r] : -1e30f;
      }
    }

    // row max: lane-local tree over 32 + cross-half merge
    float t[8];
#pragma unroll
    for (int i = 0; i < 8; i++)
      t[i] = fmaxf(fmaxf(s0[i], s0[i + 8]), fmaxf(s1[i], s1[i + 8]));
#pragma unroll
    for (int st = 4; st >= 1; st >>= 1)
#pragma unroll
      for (int i = 0; i < st; i++) t[i] = fmaxf(t[i], t[i + st]);
    float mx = t[0];
    mx = fmaxf(mx, __shfl_xor(mx, 32, 64));

    // defer-max (T13): only rescale when max grew by > 8 (exp2 domain)
    if (!__all(mx <= m + 8.0f)) {
      const float mn = fmaxf(m, mx);
      const float a = fexp2(m - mn);
      l *= a;
#pragma unroll
      for (int i = 0; i < 16; i++) { o0[i] *= a; o1[i] *= a; }
      m = mn;
    }

    // P = exp2(S - m), row-sum (per-half partial)
#pragma unroll
    for (int i = 0; i < 16; i++) {
      s0[i] = fexp2(s0[i] - m);
      s1[i] = fexp2(s1[i] - m);
    }
    float u[8];
#pragma unroll
    for (int i = 0; i < 8; i++)
      u[i] = (s0[i] + s0[i + 8]) + (s1[i] + s1[i + 8]);
#pragma unroll
    for (int st = 4; st >= 1; st >>= 1)
#pragma unroll
      for (int i = 0; i < st; i++) u[i] += u[i + st];
    l += u[0];

    // P -> bf16 B-fragments in-register (16 cvt_pk + 8 half-swaps)
    short8 pf[4];
    build_pfrag(s0, pf[0], pf[1]);
    build_pfrag(s1, pf[2], pf[3]);

    // PV: O^T[d][q] += V^T x P^T, two 32-d subtiles, 4 k-slices
    __builtin_amdgcn_s_setprio(1);
#pragma unroll
    for (int ks = 0; ks < 4; ks++) {
      const int slot = (((ks * 2 + hh) ^ sw7) * 8);
      const short8 v0 = *(const short8*)&Vc[cq * 64 + slot];
      const short8 v1 = *(const short8*)&Vc[(32 + cq) * 64 + slot];
      o0 = __builtin_amdgcn_mfma_f32_32x32x16_bf16(v0, pf[ks], o0, 0, 0, 0);
      o1 = __builtin_amdgcn_mfma_f32_32x32x16_bf16(v1, pf[ks], o1, 0, 0, 0);
    }
    __builtin_amdgcn_s_setprio(0);
  }

  // epilogue: merge per-half l, normalize, store
  const float lt = l + __shfl_xor(l, 32, 64);
  const float li = 1.f / lt;
  bf16_t* obp = O + ((size_t)b * S_ + qg) * (H_ * HD_) + h * HD_ + hh * 4;
#pragma unroll
  for (int rq = 0; rq < 4; rq++) {
    uint2 w0;
    w0.x = pk_bf16(o0[4 * rq] * li, o0[4 * rq + 1] * li);
    w0.y = pk_bf16(o0[4 * rq + 2] * li, o0[4 * rq + 3] * li);
    *(uint2*)(obp + rq * 8) = w0;
    uint2 w1;
    w1.x = pk_bf16(o1[4 * rq] * li, o1[4 * rq + 1] * li);
    w1.y = pk_bf16(o1[4 * rq + 2] * li, o1[4 * rq + 3] * li);
    *(uint2*)(obp + 32 + rq * 8) = w1;
  }
}

extern "C" void kernel_launch(void* const* d_in, const int* in_sizes, int n_in,
                              void* d_out, int out_size, void* d_ws, size_t ws_size,
                              hipStream_t stream) {
  const float* x    = (const float*)d_in[0];
  const float* cs   = (const float*)d_in[1];
  const float* sn   = (const float*)d_in[2];
  const float* wqkv = (const float*)d_in[3];
  const float* wout = (const float*)d_in[4];
  float* out = (float*)d_out;

  char* ws = (char*)d_ws;
  bf16_t*  xb    = (bf16_t*)(ws);                 // 16,777,216 B
  bf16_t*  wqkvb = (bf16_t*)(ws + 16777216);      // 12,582,912 B
  bf16_t*  woutb = (bf16_t*)(ws + 29360128);      //  8,388,608 B
  bf16_t*  qb    = (bf16_t*)(ws + 37748736);      // 16,777,216 B
  bf16_t*  kb    = (bf16_t*)(ws + 54525952);      //  4,194,304 B
  bf16_t*  vtb   = (bf16_t*)(ws + 58720256);      //  4,194,304 B
  bf16_t*  attnb = (bf16_t*)(ws + 62914560);      // 16,777,216 B
  unsigned* tab  = (unsigned*)(ws + 79691776);    //    524,288 B (total ~80 MB)

  prep<<<18944, 256, 0, stream>>>(x, xb, wqkv, wqkvb, wout, woutb, cs, sn, tab);
  gemm_qkv<<<dim3(24, 32), 256, 0, stream>>>(xb, wqkvb, tab, qb, kb, vtb);
  flash_attn<<<1024, 256, 0, stream>>>(qb, kb, vtb, attnb);
  gemm_bt<<<dim3(16, 32), 256, 0, stream>>>(attnb, woutb, out, 4096, 2048, 2048);
}

// Round 9
// 280.940 us; speedup vs baseline: 1.0207x; 1.0207x over previous
//
#include <hip/hip_runtime.h>
#include <hip/hip_fp16.h>

#define B_ 2
#define S_ 2048
#define D_ 2048
#define H_ 32
#define KV_ 8
#define HD_ 64

typedef unsigned short bf16_t;
typedef __attribute__((ext_vector_type(8))) short short8;
typedef __attribute__((ext_vector_type(4))) float floatx4;
typedef __attribute__((ext_vector_type(16))) float floatx16;

__device__ __forceinline__ bf16_t f2bf(float f) {
  union { float f; unsigned u; } c; c.f = f;
  unsigned u = c.u;
  u += 0x7fffu + ((u >> 16) & 1u);          // round-to-nearest-even
  return (bf16_t)(u >> 16);
}

__device__ __forceinline__ unsigned pk_bf16(float a, float b) {
#if __has_builtin(__builtin_amdgcn_cvt_pk_bf16_f32)
  auto v = __builtin_amdgcn_cvt_pk_bf16_f32(a, b);
  unsigned u; __builtin_memcpy(&u, &v, 4); return u;
#else
  return (unsigned)f2bf(a) | ((unsigned)f2bf(b) << 16);
#endif
}

__device__ __forceinline__ float fexp2(float x) {
#if __has_builtin(__builtin_amdgcn_exp2f)
  return __builtin_amdgcn_exp2f(x);
#else
  return exp2f(x);
#endif
}

__device__ __forceinline__ void load_lds16(const void* g, void* l) {
  __builtin_amdgcn_global_load_lds(
      (const __attribute__((address_space(1))) void*)g,
      (__attribute__((address_space(3))) void*)l, 16, 0, 0);
}

// ---------------- prep: fp32->bf16 casts + packed fp16 rope table ----------------
__device__ __forceinline__ void cvt4(const float* __restrict__ in,
                                     bf16_t* __restrict__ out, int i) {
  float4 v = ((const float4*)in)[i];
  ushort4 o;
  o.x = f2bf(v.x); o.y = f2bf(v.y); o.z = f2bf(v.z); o.w = f2bf(v.w);
  ((ushort4*)out)[i] = o;
}

__global__ __launch_bounds__(256) void prep(
    const float* __restrict__ x, bf16_t* __restrict__ xb,
    const float* __restrict__ wqkv, bf16_t* __restrict__ wqkvb,
    const float* __restrict__ wout, bf16_t* __restrict__ woutb,
    const float* __restrict__ cs, const float* __restrict__ sn,
    unsigned* __restrict__ tab) {
  const int bid = blockIdx.x;
  if (bid < 8192) {
    cvt4(x, xb, bid * 256 + threadIdx.x);
  } else if (bid < 14336) {
    cvt4(wqkv, wqkvb, (bid - 8192) * 256 + threadIdx.x);
  } else if (bid < 18432) {
    cvt4(wout, woutb, (bid - 14336) * 256 + threadIdx.x);
  } else {
    const int i = (bid - 18432) * 256 + threadIdx.x;   // 131072 entries
    __half2 h = __floats2half2_rn(cs[i], sn[i]);
    unsigned u; __builtin_memcpy(&u, &h, 4);
    tab[i] = u;
  }
}

// ---------------- bf16 GEMM: C[M,N] = A[M,K] * B^T (f32 out) ----------------
// BK=64 (half the barrier drains of BK=32), XOR-swizzled LDS:
// LDS[row][slot] = global[row][slot ^ (row&7)] (slot = 16B chunk, 8/row).
__global__ __launch_bounds__(256) void gemm_bt(
    const bf16_t* __restrict__ A, const bf16_t* __restrict__ Bm,
    float* __restrict__ C, int M, int N, int K) {
  __shared__ __attribute__((aligned(16))) bf16_t As[128 * 64];  // 16 KB
  __shared__ __attribute__((aligned(16))) bf16_t Bs[128 * 64];  // 16 KB
  const int tid = threadIdx.x;
  const int lane = tid & 63;
  const int wave = tid >> 6;
  const int bm = blockIdx.y * 128, bn = blockIdx.x * 128;
  const int wm = (wave >> 1) * 64, wn = (wave & 1) * 64;
  const int lr = lane & 15, quad = lane >> 4;

  floatx4 acc[4][4] = {};

  const bf16_t* Ab = A + (size_t)bm * K;
  const bf16_t* Bb = Bm + (size_t)bn * K;

  for (int k0 = 0; k0 < K; k0 += 64) {
    __syncthreads();
#pragma unroll
    for (int p = 0; p < 4; p++) {
      const int idx = p * 256 + tid;
      const int row = idx >> 3, sc = idx & 7;
      const int gc = sc ^ (row & 7);
      load_lds16(Ab + (size_t)row * K + k0 + gc * 8, &As[idx * 8]);
      load_lds16(Bb + (size_t)row * K + k0 + gc * 8, &Bs[idx * 8]);
    }
    __syncthreads();

#pragma unroll
    for (int ks = 0; ks < 2; ks++) {
      short8 af[4], bfr[4];
#pragma unroll
      for (int i = 0; i < 4; i++) {
        const int ra = wm + i * 16 + lr;
        const int rb = wn + i * 16 + lr;
        af[i]  = *(const short8*)&As[ra * 64 + (((ks * 4 + quad) ^ (ra & 7)) * 8)];
        bfr[i] = *(const short8*)&Bs[rb * 64 + (((ks * 4 + quad) ^ (rb & 7)) * 8)];
      }
#pragma unroll
      for (int mi = 0; mi < 4; mi++)
#pragma unroll
        for (int ni = 0; ni < 4; ni++)
          acc[mi][ni] = __builtin_amdgcn_mfma_f32_16x16x32_bf16(af[mi], bfr[ni], acc[mi][ni], 0, 0, 0);
    }
  }

#pragma unroll
  for (int mi = 0; mi < 4; mi++) {
    const int row = bm + wm + mi * 16 + quad * 4;
#pragma unroll
    for (int ni = 0; ni < 4; ni++) {
      const int col = bn + wn + ni * 16 + lr;
      float* cp = C + (size_t)row * N + col;
#pragma unroll
      for (int r = 0; r < 4; r++) cp[(size_t)r * N] = acc[mi][ni][r];
    }
  }
}

// ---------------- fused QKV GEMM + RoPE (fp16 table) + repack ----------------
// Ts transpose scratch aliases As/Bs (dead after the K-loop): LDS 32 KB
// => 4 blocks/CU. One uniform __syncthreads() after the K-loop.
__global__ __launch_bounds__(256, 4) void gemm_qkv(
    const bf16_t* __restrict__ A, const bf16_t* __restrict__ Bm,
    const unsigned* __restrict__ tab,
    bf16_t* __restrict__ q, bf16_t* __restrict__ k, bf16_t* __restrict__ vt) {
  const int K = 2048;
  __shared__ __attribute__((aligned(16))) bf16_t As[128 * 64];  // 16 KB
  __shared__ __attribute__((aligned(16))) bf16_t Bs[128 * 64];  // 16 KB
  const int tid = threadIdx.x;
  const int lane = tid & 63;
  const int wave = tid >> 6;
  const int bm = blockIdx.y * 128, bn = blockIdx.x * 128;
  const int wm = (wave >> 1) * 64, wn = (wave & 1) * 64;
  const int lr = lane & 15, quad = lane >> 4;

  floatx4 acc[4][4] = {};

  const bf16_t* Ab = A + (size_t)bm * K;
  const bf16_t* Bb = Bm + (size_t)bn * K;

  for (int k0 = 0; k0 < K; k0 += 64) {
    __syncthreads();
#pragma unroll
    for (int p = 0; p < 4; p++) {
      const int idx = p * 256 + tid;
      const int row = idx >> 3, sc = idx & 7;
      const int gc = sc ^ (row & 7);
      load_lds16(Ab + (size_t)row * K + k0 + gc * 8, &As[idx * 8]);
      load_lds16(Bb + (size_t)row * K + k0 + gc * 8, &Bs[idx * 8]);
    }
    __syncthreads();

#pragma unroll
    for (int ks = 0; ks < 2; ks++) {
      short8 af[4], bfr[4];
#pragma unroll
      for (int i = 0; i < 4; i++) {
        const int ra = wm + i * 16 + lr;
        const int rb = wn + i * 16 + lr;
        af[i]  = *(const short8*)&As[ra * 64 + (((ks * 4 + quad) ^ (ra & 7)) * 8)];
        bfr[i] = *(const short8*)&Bs[rb * 64 + (((ks * 4 + quad) ^ (rb & 7)) * 8)];
      }
#pragma unroll
      for (int mi = 0; mi < 4; mi++)
#pragma unroll
        for (int ni = 0; ni < 4; ni++)
          acc[mi][ni] = __builtin_amdgcn_mfma_f32_16x16x32_bf16(af[mi], bfr[ni], acc[mi][ni], 0, 0, 0);
    }
  }

  __syncthreads();   // uniform: As/Bs reads retired; safe to reuse as scratch

  const int f0 = bn + wn;              // wave-uniform feature base (multiple of 64)
  const int srow0 = bm + wm;
  const int bb = srow0 >> 11, s0 = srow0 & 2047;

  if (f0 < 2560) {                     // Q or K head: in-register rope
    const bool isq = (f0 < 2048);
    const float scale = isq ? 0.18033688011f : 1.0f;   // 0.125 * log2(e)
    bf16_t* dst = isq ? (q + (size_t)(bb * H_ + (f0 >> 6)) * S_ * HD_)
                      : (k + (size_t)(bb * KV_ + ((f0 - 2048) >> 6)) * S_ * HD_);
#pragma unroll
    for (int mi = 0; mi < 4; mi++) {
#pragma unroll
      for (int r = 0; r < 4; r++) {
        const int sr = s0 + mi * 16 + quad * 4 + r;
        const unsigned* tp = tab + (size_t)sr * HD_;
        bf16_t* drow = dst + (size_t)sr * HD_;
#pragma unroll
        for (int ni = 0; ni < 4; ni++) {
          const int d = ni * 16 + lr;
          const unsigned w = tp[d];
          __half2 h2; __builtin_memcpy(&h2, &w, 4);
          const float2 cf = __half22float2(h2);
          const float t = acc[mi][ni][r];
          const float oth = acc[mi][ni ^ 2][r];
          const float rot = (ni < 2) ? -oth : oth;   // d<32 iff ni<2
          drow[d] = f2bf((t * cf.x + rot * cf.y) * scale);
        }
      }
    }
  } else {                             // V head: 2-pass transpose via aliased scratch
    const int hv = (f0 - 2560) >> 6;
    // per-wave 4608 B region: waves 0-1 in As, waves 2-3 in Bs (16B-aligned)
    bf16_t* ts = (wave < 2) ? (As + wave * 2304) : (Bs + (wave - 2) * 2304);
    const int rl = lane >> 1, hf = lane & 1;
#pragma unroll
    for (int p = 0; p < 2; p++) {
#pragma unroll
      for (int nn = 0; nn < 2; nn++) {
        const int ni = 2 * p + nn;
#pragma unroll
        for (int mi = 0; mi < 4; mi++) {
          uint2 pw;
          pw.x = pk_bf16(acc[mi][ni][0], acc[mi][ni][1]);
          pw.y = pk_bf16(acc[mi][ni][2], acc[mi][ni][3]);
          *(uint2*)&ts[(nn * 16 + lr) * 72 + mi * 16 + quad * 4] = pw;
        }
      }
      // same-wave RAW/WAR: DS pipe is in-order per wave, compiler emits lgkmcnt
      bf16_t* vrow = vt + ((size_t)(bb * KV_ + hv) * HD_ + p * 32 + rl) * S_ + s0 + hf * 32;
#pragma unroll
      for (int j = 0; j < 4; j++)
        *(short8*)(vrow + j * 8) = *(const short8*)&ts[rl * 72 + hf * 32 + j * 8];
    }
  }
}

// ---------------- flash attention v9: conflict-free LDS swizzle ----------------
// Same structure as v8 (4-wave blocks, 128 q-rows, KVBLK=64 double-buffered,
// balanced Tb decode). NEW: the LDS swizzle now folds row>>3 into the slot
// rotation -- slot(r,c) = ((c ^ (r&7)) + 2*(r>>3)) & 7 -- so the 32 lanes of a
// QK/PV ds_read_b128 (rows cq, cq+8, cq+16, cq+24 share cq&7) hit all 8 bank
// groups uniformly instead of 4-way aliasing. Staging inverts the permutation
// on the global source address (rule #21: both-sides-or-neither).

__device__ __forceinline__ void stage64_4w(const bf16_t* __restrict__ gk,
                                           const bf16_t* __restrict__ gv,
                                           bf16_t* kbuf, bf16_t* vbuf, int tid) {
#pragma unroll
  for (int j = 0; j < 2; j++) {
    const int idx = j * 256 + tid;      // 512 chunks of 16B per 64x64 tile
    const int row = idx >> 3;
    const int sc  = idx & 7;
    const int gc  = ((sc - 2 * (row >> 3)) & 7) ^ (row & 7);  // inverse swizzle
    load_lds16(gk + (size_t)row * HD_ + gc * 8, kbuf + idx * 8);
    load_lds16(gv + (size_t)row * S_  + gc * 8, vbuf + idx * 8);
  }
}

// halves-exchange: x = [a.lo | b.lo], y = [a.hi | b.hi] (lanes 0-31 | 32-63)
__device__ __forceinline__ void hswap(unsigned a, unsigned b, unsigned& x, unsigned& y) {
#if __has_builtin(__builtin_amdgcn_permlane32_swap)
  auto r = __builtin_amdgcn_permlane32_swap(a, b, false, false);
  x = (unsigned)r[0]; y = (unsigned)r[1];
#else
  const unsigned pa = (unsigned)__shfl_xor((int)a, 32, 64);
  const unsigned pb = (unsigned)__shfl_xor((int)b, 32, 64);
  const bool hi = (threadIdx.x & 32) != 0;
  x = hi ? pb : a;
  y = hi ? b : pa;
#endif
}

// one k-subtile (32 k) of P in lane regs -> two PV B-fragments (k-slices of 16)
__device__ __forceinline__ void build_pfrag(const floatx16& p, short8& f0, short8& f1) {
  unsigned w[8];
  const unsigned c01 = pk_bf16(p[0], p[1]);
  const unsigned c45 = pk_bf16(p[4], p[5]);
  const unsigned c23 = pk_bf16(p[2], p[3]);
  const unsigned c67 = pk_bf16(p[6], p[7]);
  hswap(c01, c45, w[0], w[2]);
  hswap(c23, c67, w[1], w[3]);
  const unsigned d01 = pk_bf16(p[8], p[9]);
  const unsigned d45 = pk_bf16(p[12], p[13]);
  const unsigned d23 = pk_bf16(p[10], p[11]);
  const unsigned d67 = pk_bf16(p[14], p[15]);
  hswap(d01, d45, w[4], w[6]);
  hswap(d23, d67, w[5], w[7]);
  __builtin_memcpy(&f0, &w[0], 16);
  __builtin_memcpy(&f1, &w[4], 16);
}

__global__ __launch_bounds__(256, 2) void flash_attn(
    const bf16_t* __restrict__ Q,   // [B*H, S, 64] (pre-scaled by 0.125*log2e)
    const bf16_t* __restrict__ Kc,  // [B*KV, S, 64]
    const bf16_t* __restrict__ Vt,  // [B*KV, 64, S]
    bf16_t* __restrict__ O) {       // [B, S, H*64]
  __shared__ __attribute__((aligned(16))) bf16_t Ks[2 * 4096];  // 16 KB
  __shared__ __attribute__((aligned(16))) bf16_t Vs[2 * 4096];  // 16 KB -> 32 KB
  // balanced decode: bid = g*256 + j; head = XCD-grouped(j&63); c = (j>>6)&3;
  // Tb = {15-c, 11-c, 4+c, c}[g] -> per-CU k-tile total is uniform (68).
  const int bid = blockIdx.x;
  const int j = bid & 255;
  const int g = bid >> 8;
  const int c = (j >> 6) & 3;
  const int head = ((j & 7) << 3) | ((j >> 3) & 7);
  const int Tb = (g < 2) ? (15 - 4 * g - c) : (4 * (3 - g) + c);
  const int b = head >> 5, h = head & 31;
  const int kvh = b * KV_ + (h >> 2);
  const int tid = threadIdx.x;
  const int wave = tid >> 6, lane = tid & 63;
  const int cq = lane & 31, hh = lane >> 5;
  const int sw7 = lane & 7;
  const int rot = 2 * (cq >> 3);        // bank-rotation: rows cq & 32+cq agree mod 8
  const int q0 = Tb * 128 + wave * 32, qg = q0 + cq;
  const int nt = 2 * Tb + 2;            // 64-k tiles staged by the block
  const int last = 2 * Tb + (wave >> 1);  // this wave's diag tile

  const bf16_t* kb = Kc + (size_t)kvh * S_ * HD_;
  const bf16_t* vb = Vt + (size_t)kvh * HD_ * S_;

  // Q fragments (B operand): lane holds Q[q0+cq][ds*16 + hh*8 .. +8]
  const bf16_t* qp = Q + ((size_t)head * S_ + qg) * HD_ + hh * 8;
  short8 qf[4];
#pragma unroll
  for (int ds = 0; ds < 4; ds++) qf[ds] = *(const short8*)(qp + ds * 16);

  floatx16 o0 = {}, o1 = {};
  float m = -1e30f, l = 0.f;            // l kept per-half; merged at store

  stage64_4w(kb, vb, Ks, Vs, tid);

  for (int kt = 0; kt < nt; kt++) {
    __syncthreads();
    if (kt + 1 < nt)
      stage64_4w(kb + (size_t)(kt + 1) * 64 * HD_, vb + (kt + 1) * 64,
                 Ks + ((kt + 1) & 1) * 4096, Vs + ((kt + 1) & 1) * 4096, tid);
    if (kt > last) continue;            // wave-uniform; barriers still honored
    const bf16_t* Kt = Ks + (kt & 1) * 4096;
    const bf16_t* Vc = Vs + (kt & 1) * 4096;

    // QK^T: S^T[k][q], two 32-k subtiles, K summed over 4 d-slices
    floatx16 s0 = {}, s1 = {};
    __builtin_amdgcn_s_setprio(1);
#pragma unroll
    for (int ds = 0; ds < 4; ds++) {
      const int slot = ((((ds * 2 + hh) ^ sw7) + rot) & 7) * 8;
      const short8 k0 = *(const short8*)&Kt[cq * 64 + slot];
      const short8 k1 = *(const short8*)&Kt[(32 + cq) * 64 + slot];
      s0 = __builtin_amdgcn_mfma_f32_32x32x16_bf16(k0, qf[ds], s0, 0, 0, 0);
      s1 = __builtin_amdgcn_mfma_f32_32x32x16_bf16(k1, qf[ds], s1, 0, 0, 0);
    }
    __builtin_amdgcn_s_setprio(0);

    // causal mask on this wave's diag tile
    if (kt == last) {
      const int kbase = kt * 64 + 4 * hh;
#pragma unroll
      for (int r = 0; r < 16; r++) {
        const int kg = kbase + (r & 3) + 8 * (r >> 2);
        s0[r] = (kg <= qg) ? s0[r] : -1e30f;
        s1[r] = (kg + 32 <= qg) ? s1[r] : -1e30f;
      }
    }

    // row max: lane-local tree over 32 + cross-half merge
    float t[8];
#pragma unroll
    for (int i = 0; i < 8; i++)
      t[i] = fmaxf(fmaxf(s0[i], s0[i + 8]), fmaxf(s1[i], s1[i + 8]));
#pragma unroll
    for (int st = 4; st >= 1; st >>= 1)
#pragma unroll
      for (int i = 0; i < st; i++) t[i] = fmaxf(t[i], t[i + st]);
    float mx = t[0];
    mx = fmaxf(mx, __shfl_xor(mx, 32, 64));

    // defer-max (T13): only rescale when max grew by > 8 (exp2 domain)
    if (!__all(mx <= m + 8.0f)) {
      const float mn = fmaxf(m, mx);
      const float a = fexp2(m - mn);
      l *= a;
#pragma unroll
      for (int i = 0; i < 16; i++) { o0[i] *= a; o1[i] *= a; }
      m = mn;
    }

    // P = exp2(S - m), row-sum (per-half partial)
#pragma unroll
    for (int i = 0; i < 16; i++) {
      s0[i] = fexp2(s0[i] - m);
      s1[i] = fexp2(s1[i] - m);
    }
    float u[8];
#pragma unroll
    for (int i = 0; i < 8; i++)
      u[i] = (s0[i] + s0[i + 8]) + (s1[i] + s1[i + 8]);
#pragma unroll
    for (int st = 4; st >= 1; st >>= 1)
#pragma unroll
      for (int i = 0; i < st; i++) u[i] += u[i + st];
    l += u[0];

    // P -> bf16 B-fragments in-register (16 cvt_pk + 8 half-swaps)
    short8 pf[4];
    build_pfrag(s0, pf[0], pf[1]);
    build_pfrag(s1, pf[2], pf[3]);

    // PV: O^T[d][q] += V^T x P^T, two 32-d subtiles, 4 k-slices
    __builtin_amdgcn_s_setprio(1);
#pragma unroll
    for (int ks = 0; ks < 4; ks++) {
      const int slot = ((((ks * 2 + hh) ^ sw7) + rot) & 7) * 8;
      const short8 v0 = *(const short8*)&Vc[cq * 64 + slot];
      const short8 v1 = *(const short8*)&Vc[(32 + cq) * 64 + slot];
      o0 = __builtin_amdgcn_mfma_f32_32x32x16_bf16(v0, pf[ks], o0, 0, 0, 0);
      o1 = __builtin_amdgcn_mfma_f32_32x32x16_bf16(v1, pf[ks], o1, 0, 0, 0);
    }
    __builtin_amdgcn_s_setprio(0);
  }

  // epilogue: merge per-half l, normalize, store
  const float lt = l + __shfl_xor(l, 32, 64);
  const float li = 1.f / lt;
  bf16_t* obp = O + ((size_t)b * S_ + qg) * (H_ * HD_) + h * HD_ + hh * 4;
#pragma unroll
  for (int rq = 0; rq < 4; rq++) {
    uint2 w0;
    w0.x = pk_bf16(o0[4 * rq] * li, o0[4 * rq + 1] * li);
    w0.y = pk_bf16(o0[4 * rq + 2] * li, o0[4 * rq + 3] * li);
    *(uint2*)(obp + rq * 8) = w0;
    uint2 w1;
    w1.x = pk_bf16(o1[4 * rq] * li, o1[4 * rq + 1] * li);
    w1.y = pk_bf16(o1[4 * rq + 2] * li, o1[4 * rq + 3] * li);
    *(uint2*)(obp + 32 + rq * 8) = w1;
  }
}

extern "C" void kernel_launch(void* const* d_in, const int* in_sizes, int n_in,
                              void* d_out, int out_size, void* d_ws, size_t ws_size,
                              hipStream_t stream) {
  const float* x    = (const float*)d_in[0];
  const float* cs   = (const float*)d_in[1];
  const float* sn   = (const float*)d_in[2];
  const float* wqkv = (const float*)d_in[3];
  const float* wout = (const float*)d_in[4];
  float* out = (float*)d_out;

  char* ws = (char*)d_ws;
  bf16_t*  xb    = (bf16_t*)(ws);                 // 16,777,216 B
  bf16_t*  wqkvb = (bf16_t*)(ws + 16777216);      // 12,582,912 B
  bf16_t*  woutb = (bf16_t*)(ws + 29360128);      //  8,388,608 B
  bf16_t*  qb    = (bf16_t*)(ws + 37748736);      // 16,777,216 B
  bf16_t*  kb    = (bf16_t*)(ws + 54525952);      //  4,194,304 B
  bf16_t*  vtb   = (bf16_t*)(ws + 58720256);      //  4,194,304 B
  bf16_t*  attnb = (bf16_t*)(ws + 62914560);      // 16,777,216 B
  unsigned* tab  = (unsigned*)(ws + 79691776);    //    524,288 B (total ~80 MB)

  prep<<<18944, 256, 0, stream>>>(x, xb, wqkv, wqkvb, wout, woutb, cs, sn, tab);
  gemm_qkv<<<dim3(24, 32), 256, 0, stream>>>(xb, wqkvb, tab, qb, kb, vtb);
  flash_attn<<<1024, 256, 0, stream>>>(qb, kb, vtb, attnb);
  gemm_bt<<<dim3(16, 32), 256, 0, stream>>>(attnb, woutb, out, 4096, 2048, 2048);
}

// Round 10
// 278.040 us; speedup vs baseline: 1.0313x; 1.0104x over previous
//
#include <hip/hip_runtime.h>
#include <hip/hip_fp16.h>

#define B_ 2
#define S_ 2048
#define D_ 2048
#define H_ 32
#define KV_ 8
#define HD_ 64

typedef unsigned short bf16_t;
typedef __attribute__((ext_vector_type(8))) short short8;
typedef __attribute__((ext_vector_type(4))) float floatx4;
typedef __attribute__((ext_vector_type(16))) float floatx16;

__device__ __forceinline__ bf16_t f2bf(float f) {
  union { float f; unsigned u; } c; c.f = f;
  unsigned u = c.u;
  u += 0x7fffu + ((u >> 16) & 1u);          // round-to-nearest-even
  return (bf16_t)(u >> 16);
}

__device__ __forceinline__ unsigned pk_bf16(float a, float b) {
#if __has_builtin(__builtin_amdgcn_cvt_pk_bf16_f32)
  auto v = __builtin_amdgcn_cvt_pk_bf16_f32(a, b);
  unsigned u; __builtin_memcpy(&u, &v, 4); return u;
#else
  return (unsigned)f2bf(a) | ((unsigned)f2bf(b) << 16);
#endif
}

__device__ __forceinline__ float fexp2(float x) {
#if __has_builtin(__builtin_amdgcn_exp2f)
  return __builtin_amdgcn_exp2f(x);
#else
  return exp2f(x);
#endif
}

__device__ __forceinline__ void load_lds16(const void* g, void* l) {
  __builtin_amdgcn_global_load_lds(
      (const __attribute__((address_space(1))) void*)g,
      (__attribute__((address_space(3))) void*)l, 16, 0, 0);
}

// ---------------- prep: fp32->bf16 casts + packed fp16 rope table ----------------
__device__ __forceinline__ void cvt4(const float* __restrict__ in,
                                     bf16_t* __restrict__ out, int i) {
  float4 v = ((const float4*)in)[i];
  ushort4 o;
  o.x = f2bf(v.x); o.y = f2bf(v.y); o.z = f2bf(v.z); o.w = f2bf(v.w);
  ((ushort4*)out)[i] = o;
}

__global__ __launch_bounds__(256) void prep(
    const float* __restrict__ x, bf16_t* __restrict__ xb,
    const float* __restrict__ wqkv, bf16_t* __restrict__ wqkvb,
    const float* __restrict__ wout, bf16_t* __restrict__ woutb,
    const float* __restrict__ cs, const float* __restrict__ sn,
    unsigned* __restrict__ tab) {
  const int bid = blockIdx.x;
  if (bid < 8192) {
    cvt4(x, xb, bid * 256 + threadIdx.x);
  } else if (bid < 14336) {
    cvt4(wqkv, wqkvb, (bid - 8192) * 256 + threadIdx.x);
  } else if (bid < 18432) {
    cvt4(wout, woutb, (bid - 14336) * 256 + threadIdx.x);
  } else {
    const int i = (bid - 18432) * 256 + threadIdx.x;   // 131072 entries
    __half2 h = __floats2half2_rn(cs[i], sn[i]);
    unsigned u; __builtin_memcpy(&u, &h, 4);
    tab[i] = u;
  }
}

// ---------------- bf16 GEMM: C[M,N] = A[M,K] * B^T (f32 out) ----------------
// BK=64 (half the barrier drains of BK=32), XOR-swizzled LDS:
// LDS[row][slot] = global[row][slot ^ (row&7)] (slot = 16B chunk, 8/row).
__global__ __launch_bounds__(256) void gemm_bt(
    const bf16_t* __restrict__ A, const bf16_t* __restrict__ Bm,
    float* __restrict__ C, int M, int N, int K) {
  __shared__ __attribute__((aligned(16))) bf16_t As[128 * 64];  // 16 KB
  __shared__ __attribute__((aligned(16))) bf16_t Bs[128 * 64];  // 16 KB
  const int tid = threadIdx.x;
  const int lane = tid & 63;
  const int wave = tid >> 6;
  const int bm = blockIdx.y * 128, bn = blockIdx.x * 128;
  const int wm = (wave >> 1) * 64, wn = (wave & 1) * 64;
  const int lr = lane & 15, quad = lane >> 4;

  floatx4 acc[4][4] = {};

  const bf16_t* Ab = A + (size_t)bm * K;
  const bf16_t* Bb = Bm + (size_t)bn * K;

  for (int k0 = 0; k0 < K; k0 += 64) {
    __syncthreads();
#pragma unroll
    for (int p = 0; p < 4; p++) {
      const int idx = p * 256 + tid;
      const int row = idx >> 3, sc = idx & 7;
      const int gc = sc ^ (row & 7);
      load_lds16(Ab + (size_t)row * K + k0 + gc * 8, &As[idx * 8]);
      load_lds16(Bb + (size_t)row * K + k0 + gc * 8, &Bs[idx * 8]);
    }
    __syncthreads();

#pragma unroll
    for (int ks = 0; ks < 2; ks++) {
      short8 af[4], bfr[4];
#pragma unroll
      for (int i = 0; i < 4; i++) {
        const int ra = wm + i * 16 + lr;
        const int rb = wn + i * 16 + lr;
        af[i]  = *(const short8*)&As[ra * 64 + (((ks * 4 + quad) ^ (ra & 7)) * 8)];
        bfr[i] = *(const short8*)&Bs[rb * 64 + (((ks * 4 + quad) ^ (rb & 7)) * 8)];
      }
#pragma unroll
      for (int mi = 0; mi < 4; mi++)
#pragma unroll
        for (int ni = 0; ni < 4; ni++)
          acc[mi][ni] = __builtin_amdgcn_mfma_f32_16x16x32_bf16(af[mi], bfr[ni], acc[mi][ni], 0, 0, 0);
    }
  }

#pragma unroll
  for (int mi = 0; mi < 4; mi++) {
    const int row = bm + wm + mi * 16 + quad * 4;
#pragma unroll
    for (int ni = 0; ni < 4; ni++) {
      const int col = bn + wn + ni * 16 + lr;
      float* cp = C + (size_t)row * N + col;
#pragma unroll
      for (int r = 0; r < 4; r++) cp[(size_t)r * N] = acc[mi][ni][r];
    }
  }
}

// ---------------- fused QKV GEMM + RoPE (fp16 table) + repack ----------------
// Ts transpose scratch aliases As/Bs (dead after the K-loop): LDS 32 KB
// => 4 blocks/CU. One uniform __syncthreads() after the K-loop.
__global__ __launch_bounds__(256, 4) void gemm_qkv(
    const bf16_t* __restrict__ A, const bf16_t* __restrict__ Bm,
    const unsigned* __restrict__ tab,
    bf16_t* __restrict__ q, bf16_t* __restrict__ k, bf16_t* __restrict__ vt) {
  const int K = 2048;
  __shared__ __attribute__((aligned(16))) bf16_t As[128 * 64];  // 16 KB
  __shared__ __attribute__((aligned(16))) bf16_t Bs[128 * 64];  // 16 KB
  const int tid = threadIdx.x;
  const int lane = tid & 63;
  const int wave = tid >> 6;
  const int bm = blockIdx.y * 128, bn = blockIdx.x * 128;
  const int wm = (wave >> 1) * 64, wn = (wave & 1) * 64;
  const int lr = lane & 15, quad = lane >> 4;

  floatx4 acc[4][4] = {};

  const bf16_t* Ab = A + (size_t)bm * K;
  const bf16_t* Bb = Bm + (size_t)bn * K;

  for (int k0 = 0; k0 < K; k0 += 64) {
    __syncthreads();
#pragma unroll
    for (int p = 0; p < 4; p++) {
      const int idx = p * 256 + tid;
      const int row = idx >> 3, sc = idx & 7;
      const int gc = sc ^ (row & 7);
      load_lds16(Ab + (size_t)row * K + k0 + gc * 8, &As[idx * 8]);
      load_lds16(Bb + (size_t)row * K + k0 + gc * 8, &Bs[idx * 8]);
    }
    __syncthreads();

#pragma unroll
    for (int ks = 0; ks < 2; ks++) {
      short8 af[4], bfr[4];
#pragma unroll
      for (int i = 0; i < 4; i++) {
        const int ra = wm + i * 16 + lr;
        const int rb = wn + i * 16 + lr;
        af[i]  = *(const short8*)&As[ra * 64 + (((ks * 4 + quad) ^ (ra & 7)) * 8)];
        bfr[i] = *(const short8*)&Bs[rb * 64 + (((ks * 4 + quad) ^ (rb & 7)) * 8)];
      }
#pragma unroll
      for (int mi = 0; mi < 4; mi++)
#pragma unroll
        for (int ni = 0; ni < 4; ni++)
          acc[mi][ni] = __builtin_amdgcn_mfma_f32_16x16x32_bf16(af[mi], bfr[ni], acc[mi][ni], 0, 0, 0);
    }
  }

  __syncthreads();   // uniform: As/Bs reads retired; safe to reuse as scratch

  const int f0 = bn + wn;              // wave-uniform feature base (multiple of 64)
  const int srow0 = bm + wm;
  const int bb = srow0 >> 11, s0 = srow0 & 2047;

  if (f0 < 2560) {                     // Q or K head: in-register rope
    const bool isq = (f0 < 2048);
    const float scale = isq ? 0.18033688011f : 1.0f;   // 0.125 * log2(e)
    bf16_t* dst = isq ? (q + (size_t)(bb * H_ + (f0 >> 6)) * S_ * HD_)
                      : (k + (size_t)(bb * KV_ + ((f0 - 2048) >> 6)) * S_ * HD_);
#pragma unroll
    for (int mi = 0; mi < 4; mi++) {
#pragma unroll
      for (int r = 0; r < 4; r++) {
        const int sr = s0 + mi * 16 + quad * 4 + r;
        const unsigned* tp = tab + (size_t)sr * HD_;
        bf16_t* drow = dst + (size_t)sr * HD_;
#pragma unroll
        for (int ni = 0; ni < 4; ni++) {
          const int d = ni * 16 + lr;
          const unsigned w = tp[d];
          __half2 h2; __builtin_memcpy(&h2, &w, 4);
          const float2 cf = __half22float2(h2);
          const float t = acc[mi][ni][r];
          const float oth = acc[mi][ni ^ 2][r];
          const float rot = (ni < 2) ? -oth : oth;   // d<32 iff ni<2
          drow[d] = f2bf((t * cf.x + rot * cf.y) * scale);
        }
      }
    }
  } else {                             // V head: 2-pass transpose via aliased scratch
    const int hv = (f0 - 2560) >> 6;
    // per-wave 4608 B region: waves 0-1 in As, waves 2-3 in Bs (16B-aligned)
    bf16_t* ts = (wave < 2) ? (As + wave * 2304) : (Bs + (wave - 2) * 2304);
    const int rl = lane >> 1, hf = lane & 1;
#pragma unroll
    for (int p = 0; p < 2; p++) {
#pragma unroll
      for (int nn = 0; nn < 2; nn++) {
        const int ni = 2 * p + nn;
#pragma unroll
        for (int mi = 0; mi < 4; mi++) {
          uint2 pw;
          pw.x = pk_bf16(acc[mi][ni][0], acc[mi][ni][1]);
          pw.y = pk_bf16(acc[mi][ni][2], acc[mi][ni][3]);
          *(uint2*)&ts[(nn * 16 + lr) * 72 + mi * 16 + quad * 4] = pw;
        }
      }
      // same-wave RAW/WAR: DS pipe is in-order per wave, compiler emits lgkmcnt
      bf16_t* vrow = vt + ((size_t)(bb * KV_ + hv) * HD_ + p * 32 + rl) * S_ + s0 + hf * 32;
#pragma unroll
      for (int j = 0; j < 4; j++)
        *(short8*)(vrow + j * 8) = *(const short8*)&ts[rl * 72 + hf * 32 + j * 8];
    }
  }
}

// ---------------- flash attention v10: v8 swizzle (measured best) + max3 tree ----
// 4-wave blocks, 128 q-rows, KVBLK=64 double-buffered, balanced Tb decode.
// LDS swizzle reverted to v8's LDS[r][sc]=g[r][sc^(r&7)] (v9's rotation tripled
// bank conflicts: 4.33M -> 12.98M measured; v8 is the empirical floor for this
// access shape). Row-max tree regrouped into 3-input fmaxf triples so clang
// fuses v_max3_f32 (T17): 31 -> ~20 VALU ops per tile.

__device__ __forceinline__ void stage64_4w(const bf16_t* __restrict__ gk,
                                           const bf16_t* __restrict__ gv,
                                           bf16_t* kbuf, bf16_t* vbuf, int tid) {
#pragma unroll
  for (int j = 0; j < 2; j++) {
    const int idx = j * 256 + tid;      // 512 chunks of 16B per 64x64 tile
    const int row = idx >> 3;
    const int sc  = idx & 7;
    const int gc  = sc ^ (row & 7);
    load_lds16(gk + (size_t)row * HD_ + gc * 8, kbuf + idx * 8);
    load_lds16(gv + (size_t)row * S_  + gc * 8, vbuf + idx * 8);
  }
}

// halves-exchange: x = [a.lo | b.lo], y = [a.hi | b.hi] (lanes 0-31 | 32-63)
__device__ __forceinline__ void hswap(unsigned a, unsigned b, unsigned& x, unsigned& y) {
#if __has_builtin(__builtin_amdgcn_permlane32_swap)
  auto r = __builtin_amdgcn_permlane32_swap(a, b, false, false);
  x = (unsigned)r[0]; y = (unsigned)r[1];
#else
  const unsigned pa = (unsigned)__shfl_xor((int)a, 32, 64);
  const unsigned pb = (unsigned)__shfl_xor((int)b, 32, 64);
  const bool hi = (threadIdx.x & 32) != 0;
  x = hi ? pb : a;
  y = hi ? b : pa;
#endif
}

// one k-subtile (32 k) of P in lane regs -> two PV B-fragments (k-slices of 16)
__device__ __forceinline__ void build_pfrag(const floatx16& p, short8& f0, short8& f1) {
  unsigned w[8];
  const unsigned c01 = pk_bf16(p[0], p[1]);
  const unsigned c45 = pk_bf16(p[4], p[5]);
  const unsigned c23 = pk_bf16(p[2], p[3]);
  const unsigned c67 = pk_bf16(p[6], p[7]);
  hswap(c01, c45, w[0], w[2]);
  hswap(c23, c67, w[1], w[3]);
  const unsigned d01 = pk_bf16(p[8], p[9]);
  const unsigned d45 = pk_bf16(p[12], p[13]);
  const unsigned d23 = pk_bf16(p[10], p[11]);
  const unsigned d67 = pk_bf16(p[14], p[15]);
  hswap(d01, d45, w[4], w[6]);
  hswap(d23, d67, w[5], w[7]);
  __builtin_memcpy(&f0, &w[0], 16);
  __builtin_memcpy(&f1, &w[4], 16);
}

__global__ __launch_bounds__(256, 2) void flash_attn(
    const bf16_t* __restrict__ Q,   // [B*H, S, 64] (pre-scaled by 0.125*log2e)
    const bf16_t* __restrict__ Kc,  // [B*KV, S, 64]
    const bf16_t* __restrict__ Vt,  // [B*KV, 64, S]
    bf16_t* __restrict__ O) {       // [B, S, H*64]
  __shared__ __attribute__((aligned(16))) bf16_t Ks[2 * 4096];  // 16 KB
  __shared__ __attribute__((aligned(16))) bf16_t Vs[2 * 4096];  // 16 KB -> 32 KB
  // balanced decode: bid = g*256 + j; head = XCD-grouped(j&63); c = (j>>6)&3;
  // Tb = {15-c, 11-c, 4+c, c}[g] -> per-CU k-tile total is uniform (68).
  const int bid = blockIdx.x;
  const int j = bid & 255;
  const int g = bid >> 8;
  const int c = (j >> 6) & 3;
  const int head = ((j & 7) << 3) | ((j >> 3) & 7);
  const int Tb = (g < 2) ? (15 - 4 * g - c) : (4 * (3 - g) + c);
  const int b = head >> 5, h = head & 31;
  const int kvh = b * KV_ + (h >> 2);
  const int tid = threadIdx.x;
  const int wave = tid >> 6, lane = tid & 63;
  const int cq = lane & 31, hh = lane >> 5;
  const int sw7 = lane & 7;
  const int q0 = Tb * 128 + wave * 32, qg = q0 + cq;
  const int nt = 2 * Tb + 2;            // 64-k tiles staged by the block
  const int last = 2 * Tb + (wave >> 1);  // this wave's diag tile

  const bf16_t* kb = Kc + (size_t)kvh * S_ * HD_;
  const bf16_t* vb = Vt + (size_t)kvh * HD_ * S_;

  // Q fragments (B operand): lane holds Q[q0+cq][ds*16 + hh*8 .. +8]
  const bf16_t* qp = Q + ((size_t)head * S_ + qg) * HD_ + hh * 8;
  short8 qf[4];
#pragma unroll
  for (int ds = 0; ds < 4; ds++) qf[ds] = *(const short8*)(qp + ds * 16);

  floatx16 o0 = {}, o1 = {};
  float m = -1e30f, l = 0.f;            // l kept per-half; merged at store

  stage64_4w(kb, vb, Ks, Vs, tid);

  for (int kt = 0; kt < nt; kt++) {
    __syncthreads();
    if (kt + 1 < nt)
      stage64_4w(kb + (size_t)(kt + 1) * 64 * HD_, vb + (kt + 1) * 64,
                 Ks + ((kt + 1) & 1) * 4096, Vs + ((kt + 1) & 1) * 4096, tid);
    if (kt > last) continue;            // wave-uniform; barriers still honored
    const bf16_t* Kt = Ks + (kt & 1) * 4096;
    const bf16_t* Vc = Vs + (kt & 1) * 4096;

    // QK^T: S^T[k][q], two 32-k subtiles, K summed over 4 d-slices
    floatx16 s0 = {}, s1 = {};
    __builtin_amdgcn_s_setprio(1);
#pragma unroll
    for (int ds = 0; ds < 4; ds++) {
      const int slot = (((ds * 2 + hh) ^ sw7) * 8);
      const short8 k0 = *(const short8*)&Kt[cq * 64 + slot];
      const short8 k1 = *(const short8*)&Kt[(32 + cq) * 64 + slot];
      s0 = __builtin_amdgcn_mfma_f32_32x32x16_bf16(k0, qf[ds], s0, 0, 0, 0);
      s1 = __builtin_amdgcn_mfma_f32_32x32x16_bf16(k1, qf[ds], s1, 0, 0, 0);
    }
    __builtin_amdgcn_s_setprio(0);

    // causal mask on this wave's diag tile
    if (kt == last) {
      const int kbase = kt * 64 + 4 * hh;
#pragma unroll
      for (int r = 0; r < 16; r++) {
        const int kg = kbase + (r & 3) + 8 * (r >> 2);
        s0[r] = (kg <= qg) ? s0[r] : -1e30f;
        s1[r] = (kg + 32 <= qg) ? s1[r] : -1e30f;
      }
    }

    // row max: 3-input groupings -> v_max3_f32 fusion (T17)
    float t[8];
#pragma unroll
    for (int i = 0; i < 8; i++)
      t[i] = fmaxf(fmaxf(fmaxf(s0[i], s0[i + 8]), s1[i]), s1[i + 8]);
    const float v0 = fmaxf(fmaxf(t[0], t[1]), t[2]);
    const float v1 = fmaxf(fmaxf(t[3], t[4]), t[5]);
    const float v2 = fmaxf(fmaxf(t[6], t[7]), v0);
    float mx = fmaxf(v1, v2);
    mx = fmaxf(mx, __shfl_xor(mx, 32, 64));

    // defer-max (T13): only rescale when max grew by > 8 (exp2 domain)
    if (!__all(mx <= m + 8.0f)) {
      const float mn = fmaxf(m, mx);
      const float a = fexp2(m - mn);
      l *= a;
#pragma unroll
      for (int i = 0; i < 16; i++) { o0[i] *= a; o1[i] *= a; }
      m = mn;
    }

    // P = exp2(S - m), row-sum (per-half partial)
#pragma unroll
    for (int i = 0; i < 16; i++) {
      s0[i] = fexp2(s0[i] - m);
      s1[i] = fexp2(s1[i] - m);
    }
    float u[8];
#pragma unroll
    for (int i = 0; i < 8; i++)
      u[i] = (s0[i] + s0[i + 8]) + (s1[i] + s1[i + 8]);
#pragma unroll
    for (int st = 4; st >= 1; st >>= 1)
#pragma unroll
      for (int i = 0; i < st; i++) u[i] += u[i + st];
    l += u[0];

    // P -> bf16 B-fragments in-register (16 cvt_pk + 8 half-swaps)
    short8 pf[4];
    build_pfrag(s0, pf[0], pf[1]);
    build_pfrag(s1, pf[2], pf[3]);

    // PV: O^T[d][q] += V^T x P^T, two 32-d subtiles, 4 k-slices
    __builtin_amdgcn_s_setprio(1);
#pragma unroll
    for (int ks = 0; ks < 4; ks++) {
      const int slot = (((ks * 2 + hh) ^ sw7) * 8);
      const short8 v0f = *(const short8*)&Vc[cq * 64 + slot];
      const short8 v1f = *(const short8*)&Vc[(32 + cq) * 64 + slot];
      o0 = __builtin_amdgcn_mfma_f32_32x32x16_bf16(v0f, pf[ks], o0, 0, 0, 0);
      o1 = __builtin_amdgcn_mfma_f32_32x32x16_bf16(v1f, pf[ks], o1, 0, 0, 0);
    }
    __builtin_amdgcn_s_setprio(0);
  }

  // epilogue: merge per-half l, normalize, store
  const float lt = l + __shfl_xor(l, 32, 64);
  const float li = 1.f / lt;
  bf16_t* obp = O + ((size_t)b * S_ + qg) * (H_ * HD_) + h * HD_ + hh * 4;
#pragma unroll
  for (int rq = 0; rq < 4; rq++) {
    uint2 w0;
    w0.x = pk_bf16(o0[4 * rq] * li, o0[4 * rq + 1] * li);
    w0.y = pk_bf16(o0[4 * rq + 2] * li, o0[4 * rq + 3] * li);
    *(uint2*)(obp + rq * 8) = w0;
    uint2 w1;
    w1.x = pk_bf16(o1[4 * rq] * li, o1[4 * rq + 1] * li);
    w1.y = pk_bf16(o1[4 * rq + 2] * li, o1[4 * rq + 3] * li);
    *(uint2*)(obp + 32 + rq * 8) = w1;
  }
}

extern "C" void kernel_launch(void* const* d_in, const int* in_sizes, int n_in,
                              void* d_out, int out_size, void* d_ws, size_t ws_size,
                              hipStream_t stream) {
  const float* x    = (const float*)d_in[0];
  const float* cs   = (const float*)d_in[1];
  const float* sn   = (const float*)d_in[2];
  const float* wqkv = (const float*)d_in[3];
  const float* wout = (const float*)d_in[4];
  float* out = (float*)d_out;

  char* ws = (char*)d_ws;
  bf16_t*  xb    = (bf16_t*)(ws);                 // 16,777,216 B
  bf16_t*  wqkvb = (bf16_t*)(ws + 16777216);      // 12,582,912 B
  bf16_t*  woutb = (bf16_t*)(ws + 29360128);      //  8,388,608 B
  bf16_t*  qb    = (bf16_t*)(ws + 37748736);      // 16,777,216 B
  bf16_t*  kb    = (bf16_t*)(ws + 54525952);      //  4,194,304 B
  bf16_t*  vtb   = (bf16_t*)(ws + 58720256);      //  4,194,304 B
  bf16_t*  attnb = (bf16_t*)(ws + 62914560);      // 16,777,216 B
  unsigned* tab  = (unsigned*)(ws + 79691776);    //    524,288 B (total ~80 MB)

  prep<<<18944, 256, 0, stream>>>(x, xb, wqkv, wqkvb, wout, woutb, cs, sn, tab);
  gemm_qkv<<<dim3(24, 32), 256, 0, stream>>>(xb, wqkvb, tab, qb, kb, vtb);
  flash_attn<<<1024, 256, 0, stream>>>(qb, kb, vtb, attnb);
  gemm_bt<<<dim3(16, 32), 256, 0, stream>>>(attnb, woutb, out, 4096, 2048, 2048);
}

// Round 11
// 269.502 us; speedup vs baseline: 1.0640x; 1.0317x over previous
//
#include <hip/hip_runtime.h>
#include <hip/hip_fp16.h>

#define B_ 2
#define S_ 2048
#define D_ 2048
#define H_ 32
#define KV_ 8
#define HD_ 64

typedef unsigned short bf16_t;
typedef __attribute__((ext_vector_type(8))) short short8;
typedef __attribute__((ext_vector_type(4))) float floatx4;
typedef __attribute__((ext_vector_type(16))) float floatx16;

__device__ __forceinline__ bf16_t f2bf(float f) {
  union { float f; unsigned u; } c; c.f = f;
  unsigned u = c.u;
  u += 0x7fffu + ((u >> 16) & 1u);          // round-to-nearest-even
  return (bf16_t)(u >> 16);
}

__device__ __forceinline__ unsigned pk_bf16(float a, float b) {
#if __has_builtin(__builtin_amdgcn_cvt_pk_bf16_f32)
  auto v = __builtin_amdgcn_cvt_pk_bf16_f32(a, b);
  unsigned u; __builtin_memcpy(&u, &v, 4); return u;
#else
  return (unsigned)f2bf(a) | ((unsigned)f2bf(b) << 16);
#endif
}

__device__ __forceinline__ float fexp2(float x) {
#if __has_builtin(__builtin_amdgcn_exp2f)
  return __builtin_amdgcn_exp2f(x);
#else
  return exp2f(x);
#endif
}

__device__ __forceinline__ void load_lds16(const void* g, void* l) {
  __builtin_amdgcn_global_load_lds(
      (const __attribute__((address_space(1))) void*)g,
      (__attribute__((address_space(3))) void*)l, 16, 0, 0);
}

// ---------------- prep: fp32->bf16 casts + packed fp16 rope table ----------------
__device__ __forceinline__ void cvt4(const float* __restrict__ in,
                                     bf16_t* __restrict__ out, int i) {
  float4 v = ((const float4*)in)[i];
  ushort4 o;
  o.x = f2bf(v.x); o.y = f2bf(v.y); o.z = f2bf(v.z); o.w = f2bf(v.w);
  ((ushort4*)out)[i] = o;
}

__global__ __launch_bounds__(256) void prep(
    const float* __restrict__ x, bf16_t* __restrict__ xb,
    const float* __restrict__ wqkv, bf16_t* __restrict__ wqkvb,
    const float* __restrict__ wout, bf16_t* __restrict__ woutb,
    const float* __restrict__ cs, const float* __restrict__ sn,
    unsigned* __restrict__ tab) {
  const int bid = blockIdx.x;
  if (bid < 8192) {
    cvt4(x, xb, bid * 256 + threadIdx.x);
  } else if (bid < 14336) {
    cvt4(wqkv, wqkvb, (bid - 8192) * 256 + threadIdx.x);
  } else if (bid < 18432) {
    cvt4(wout, woutb, (bid - 14336) * 256 + threadIdx.x);
  } else {
    const int i = (bid - 18432) * 256 + threadIdx.x;   // 131072 entries
    __half2 h = __floats2half2_rn(cs[i], sn[i]);
    unsigned u; __builtin_memcpy(&u, &h, 4);
    tab[i] = u;
  }
}

// ---------------- bf16 GEMM: C[M,N] = A[M,K] * B^T (f32 out) ----------------
// v2: 64x128 tiles -> grid 1024 blocks = 4 blocks/CU (was 512 = 2/CU; more
// resident blocks to hide the per-K-step vmcnt(0)+barrier drain). BK=64,
// XOR-swizzled LDS: LDS[row][slot] = global[row][slot ^ (row&7)].
__global__ __launch_bounds__(256) void gemm_bt(
    const bf16_t* __restrict__ A, const bf16_t* __restrict__ Bm,
    float* __restrict__ C, int M, int N, int K) {
  __shared__ __attribute__((aligned(16))) bf16_t As[64 * 64];   //  8 KB
  __shared__ __attribute__((aligned(16))) bf16_t Bs[128 * 64];  // 16 KB
  const int tid = threadIdx.x;
  const int lane = tid & 63;
  const int wave = tid >> 6;
  const int bm = blockIdx.y * 64, bn = blockIdx.x * 128;
  const int wm = (wave >> 1) * 32, wn = (wave & 1) * 64;
  const int lr = lane & 15, quad = lane >> 4;

  floatx4 acc[2][4] = {};

  const bf16_t* Ab = A + (size_t)bm * K;
  const bf16_t* Bb = Bm + (size_t)bn * K;

  for (int k0 = 0; k0 < K; k0 += 64) {
    __syncthreads();
#pragma unroll
    for (int p = 0; p < 2; p++) {
      const int idx = p * 256 + tid;          // 512 chunks: A 64 rows x 8
      const int row = idx >> 3, sc = idx & 7;
      const int gc = sc ^ (row & 7);
      load_lds16(Ab + (size_t)row * K + k0 + gc * 8, &As[idx * 8]);
    }
#pragma unroll
    for (int p = 0; p < 4; p++) {
      const int idx = p * 256 + tid;          // 1024 chunks: B 128 rows x 8
      const int row = idx >> 3, sc = idx & 7;
      const int gc = sc ^ (row & 7);
      load_lds16(Bb + (size_t)row * K + k0 + gc * 8, &Bs[idx * 8]);
    }
    __syncthreads();

#pragma unroll
    for (int ks = 0; ks < 2; ks++) {
      short8 af[2], bfr[4];
#pragma unroll
      for (int i = 0; i < 2; i++) {
        const int ra = wm + i * 16 + lr;
        af[i] = *(const short8*)&As[ra * 64 + (((ks * 4 + quad) ^ (ra & 7)) * 8)];
      }
#pragma unroll
      for (int i = 0; i < 4; i++) {
        const int rb = wn + i * 16 + lr;
        bfr[i] = *(const short8*)&Bs[rb * 64 + (((ks * 4 + quad) ^ (rb & 7)) * 8)];
      }
#pragma unroll
      for (int mi = 0; mi < 2; mi++)
#pragma unroll
        for (int ni = 0; ni < 4; ni++)
          acc[mi][ni] = __builtin_amdgcn_mfma_f32_16x16x32_bf16(af[mi], bfr[ni], acc[mi][ni], 0, 0, 0);
    }
  }

#pragma unroll
  for (int mi = 0; mi < 2; mi++) {
    const int row = bm + wm + mi * 16 + quad * 4;
#pragma unroll
    for (int ni = 0; ni < 4; ni++) {
      const int col = bn + wn + ni * 16 + lr;
      float* cp = C + (size_t)row * N + col;
#pragma unroll
      for (int r = 0; r < 4; r++) cp[(size_t)r * N] = acc[mi][ni][r];
    }
  }
}

// ---------------- fused QKV GEMM + RoPE (fp16 table) + repack ----------------
// Ts transpose scratch aliases As/Bs (dead after the K-loop): LDS 32 KB
// => 4 blocks/CU. One uniform __syncthreads() after the K-loop.
__global__ __launch_bounds__(256, 4) void gemm_qkv(
    const bf16_t* __restrict__ A, const bf16_t* __restrict__ Bm,
    const unsigned* __restrict__ tab,
    bf16_t* __restrict__ q, bf16_t* __restrict__ k, bf16_t* __restrict__ vt) {
  const int K = 2048;
  __shared__ __attribute__((aligned(16))) bf16_t As[128 * 64];  // 16 KB
  __shared__ __attribute__((aligned(16))) bf16_t Bs[128 * 64];  // 16 KB
  const int tid = threadIdx.x;
  const int lane = tid & 63;
  const int wave = tid >> 6;
  const int bm = blockIdx.y * 128, bn = blockIdx.x * 128;
  const int wm = (wave >> 1) * 64, wn = (wave & 1) * 64;
  const int lr = lane & 15, quad = lane >> 4;

  floatx4 acc[4][4] = {};

  const bf16_t* Ab = A + (size_t)bm * K;
  const bf16_t* Bb = Bm + (size_t)bn * K;

  for (int k0 = 0; k0 < K; k0 += 64) {
    __syncthreads();
#pragma unroll
    for (int p = 0; p < 4; p++) {
      const int idx = p * 256 + tid;
      const int row = idx >> 3, sc = idx & 7;
      const int gc = sc ^ (row & 7);
      load_lds16(Ab + (size_t)row * K + k0 + gc * 8, &As[idx * 8]);
      load_lds16(Bb + (size_t)row * K + k0 + gc * 8, &Bs[idx * 8]);
    }
    __syncthreads();

#pragma unroll
    for (int ks = 0; ks < 2; ks++) {
      short8 af[4], bfr[4];
#pragma unroll
      for (int i = 0; i < 4; i++) {
        const int ra = wm + i * 16 + lr;
        const int rb = wn + i * 16 + lr;
        af[i]  = *(const short8*)&As[ra * 64 + (((ks * 4 + quad) ^ (ra & 7)) * 8)];
        bfr[i] = *(const short8*)&Bs[rb * 64 + (((ks * 4 + quad) ^ (rb & 7)) * 8)];
      }
#pragma unroll
      for (int mi = 0; mi < 4; mi++)
#pragma unroll
        for (int ni = 0; ni < 4; ni++)
          acc[mi][ni] = __builtin_amdgcn_mfma_f32_16x16x32_bf16(af[mi], bfr[ni], acc[mi][ni], 0, 0, 0);
    }
  }

  __syncthreads();   // uniform: As/Bs reads retired; safe to reuse as scratch

  const int f0 = bn + wn;              // wave-uniform feature base (multiple of 64)
  const int srow0 = bm + wm;
  const int bb = srow0 >> 11, s0 = srow0 & 2047;

  if (f0 < 2560) {                     // Q or K head: in-register rope
    const bool isq = (f0 < 2048);
    const float scale = isq ? 0.18033688011f : 1.0f;   // 0.125 * log2(e)
    bf16_t* dst = isq ? (q + (size_t)(bb * H_ + (f0 >> 6)) * S_ * HD_)
                      : (k + (size_t)(bb * KV_ + ((f0 - 2048) >> 6)) * S_ * HD_);
#pragma unroll
    for (int mi = 0; mi < 4; mi++) {
#pragma unroll
      for (int r = 0; r < 4; r++) {
        const int sr = s0 + mi * 16 + quad * 4 + r;
        const unsigned* tp = tab + (size_t)sr * HD_;
        bf16_t* drow = dst + (size_t)sr * HD_;
#pragma unroll
        for (int ni = 0; ni < 4; ni++) {
          const int d = ni * 16 + lr;
          const unsigned w = tp[d];
          __half2 h2; __builtin_memcpy(&h2, &w, 4);
          const float2 cf = __half22float2(h2);
          const float t = acc[mi][ni][r];
          const float oth = acc[mi][ni ^ 2][r];
          const float rot = (ni < 2) ? -oth : oth;   // d<32 iff ni<2
          drow[d] = f2bf((t * cf.x + rot * cf.y) * scale);
        }
      }
    }
  } else {                             // V head: 2-pass transpose via aliased scratch
    const int hv = (f0 - 2560) >> 6;
    // per-wave 4608 B region: waves 0-1 in As, waves 2-3 in Bs (16B-aligned)
    bf16_t* ts = (wave < 2) ? (As + wave * 2304) : (Bs + (wave - 2) * 2304);
    const int rl = lane >> 1, hf = lane & 1;
#pragma unroll
    for (int p = 0; p < 2; p++) {
#pragma unroll
      for (int nn = 0; nn < 2; nn++) {
        const int ni = 2 * p + nn;
#pragma unroll
        for (int mi = 0; mi < 4; mi++) {
          uint2 pw;
          pw.x = pk_bf16(acc[mi][ni][0], acc[mi][ni][1]);
          pw.y = pk_bf16(acc[mi][ni][2], acc[mi][ni][3]);
          *(uint2*)&ts[(nn * 16 + lr) * 72 + mi * 16 + quad * 4] = pw;
        }
      }
      // same-wave RAW/WAR: DS pipe is in-order per wave, compiler emits lgkmcnt
      bf16_t* vrow = vt + ((size_t)(bb * KV_ + hv) * HD_ + p * 32 + rl) * S_ + s0 + hf * 32;
#pragma unroll
      for (int j = 0; j < 4; j++)
        *(short8*)(vrow + j * 8) = *(const short8*)&ts[rl * 72 + hf * 32 + j * 8];
    }
  }
}

// ---------------- flash attention v11: v10 + permlane cross-half merges ----------
// 4-wave blocks, 128 q-rows, KVBLK=64 double-buffered, balanced Tb decode,
// v8 LDS swizzle (measured floor), max3 tree. NEW: the per-tile cross-half
// max merge and the epilogue l merge use permlane32_swap (1 instr) instead of
// __shfl_xor(...,32) (ds_bpermute + addr setup).

__device__ __forceinline__ void stage64_4w(const bf16_t* __restrict__ gk,
                                           const bf16_t* __restrict__ gv,
                                           bf16_t* kbuf, bf16_t* vbuf, int tid) {
#pragma unroll
  for (int j = 0; j < 2; j++) {
    const int idx = j * 256 + tid;      // 512 chunks of 16B per 64x64 tile
    const int row = idx >> 3;
    const int sc  = idx & 7;
    const int gc  = sc ^ (row & 7);
    load_lds16(gk + (size_t)row * HD_ + gc * 8, kbuf + idx * 8);
    load_lds16(gv + (size_t)row * S_  + gc * 8, vbuf + idx * 8);
  }
}

// halves-exchange: x = [a.lo | b.lo], y = [a.hi | b.hi] (lanes 0-31 | 32-63)
__device__ __forceinline__ void hswap(unsigned a, unsigned b, unsigned& x, unsigned& y) {
#if __has_builtin(__builtin_amdgcn_permlane32_swap)
  auto r = __builtin_amdgcn_permlane32_swap(a, b, false, false);
  x = (unsigned)r[0]; y = (unsigned)r[1];
#else
  const unsigned pa = (unsigned)__shfl_xor((int)a, 32, 64);
  const unsigned pb = (unsigned)__shfl_xor((int)b, 32, 64);
  const bool hi = (threadIdx.x & 32) != 0;
  x = hi ? pb : a;
  y = hi ? b : pa;
#endif
}

// cross-half (lanes i <-> i+32) max / sum of a scalar via one permlane swap
__device__ __forceinline__ float xhalf_max(float v) {
  unsigned a; __builtin_memcpy(&a, &v, 4);
  unsigned x, y; hswap(a, a, x, y);
  float fx, fy; __builtin_memcpy(&fx, &x, 4); __builtin_memcpy(&fy, &y, 4);
  return fmaxf(fx, fy);
}
__device__ __forceinline__ float xhalf_sum(float v) {
  unsigned a; __builtin_memcpy(&a, &v, 4);
  unsigned x, y; hswap(a, a, x, y);
  float fx, fy; __builtin_memcpy(&fx, &x, 4); __builtin_memcpy(&fy, &y, 4);
  return fx + fy;
}

// one k-subtile (32 k) of P in lane regs -> two PV B-fragments (k-slices of 16)
__device__ __forceinline__ void build_pfrag(const floatx16& p, short8& f0, short8& f1) {
  unsigned w[8];
  const unsigned c01 = pk_bf16(p[0], p[1]);
  const unsigned c45 = pk_bf16(p[4], p[5]);
  const unsigned c23 = pk_bf16(p[2], p[3]);
  const unsigned c67 = pk_bf16(p[6], p[7]);
  hswap(c01, c45, w[0], w[2]);
  hswap(c23, c67, w[1], w[3]);
  const unsigned d01 = pk_bf16(p[8], p[9]);
  const unsigned d45 = pk_bf16(p[12], p[13]);
  const unsigned d23 = pk_bf16(p[10], p[11]);
  const unsigned d67 = pk_bf16(p[14], p[15]);
  hswap(d01, d45, w[4], w[6]);
  hswap(d23, d67, w[5], w[7]);
  __builtin_memcpy(&f0, &w[0], 16);
  __builtin_memcpy(&f1, &w[4], 16);
}

__global__ __launch_bounds__(256, 2) void flash_attn(
    const bf16_t* __restrict__ Q,   // [B*H, S, 64] (pre-scaled by 0.125*log2e)
    const bf16_t* __restrict__ Kc,  // [B*KV, S, 64]
    const bf16_t* __restrict__ Vt,  // [B*KV, 64, S]
    bf16_t* __restrict__ O) {       // [B, S, H*64]
  __shared__ __attribute__((aligned(16))) bf16_t Ks[2 * 4096];  // 16 KB
  __shared__ __attribute__((aligned(16))) bf16_t Vs[2 * 4096];  // 16 KB -> 32 KB
  // balanced decode: bid = g*256 + j; head = XCD-grouped(j&63); c = (j>>6)&3;
  // Tb = {15-c, 11-c, 4+c, c}[g] -> per-CU k-tile total is uniform (68).
  const int bid = blockIdx.x;
  const int j = bid & 255;
  const int g = bid >> 8;
  const int c = (j >> 6) & 3;
  const int head = ((j & 7) << 3) | ((j >> 3) & 7);
  const int Tb = (g < 2) ? (15 - 4 * g - c) : (4 * (3 - g) + c);
  const int b = head >> 5, h = head & 31;
  const int kvh = b * KV_ + (h >> 2);
  const int tid = threadIdx.x;
  const int wave = tid >> 6, lane = tid & 63;
  const int cq = lane & 31, hh = lane >> 5;
  const int sw7 = lane & 7;
  const int q0 = Tb * 128 + wave * 32, qg = q0 + cq;
  const int nt = 2 * Tb + 2;            // 64-k tiles staged by the block
  const int last = 2 * Tb + (wave >> 1);  // this wave's diag tile

  const bf16_t* kb = Kc + (size_t)kvh * S_ * HD_;
  const bf16_t* vb = Vt + (size_t)kvh * HD_ * S_;

  // Q fragments (B operand): lane holds Q[q0+cq][ds*16 + hh*8 .. +8]
  const bf16_t* qp = Q + ((size_t)head * S_ + qg) * HD_ + hh * 8;
  short8 qf[4];
#pragma unroll
  for (int ds = 0; ds < 4; ds++) qf[ds] = *(const short8*)(qp + ds * 16);

  floatx16 o0 = {}, o1 = {};
  float m = -1e30f, l = 0.f;            // l kept per-half; merged at store

  stage64_4w(kb, vb, Ks, Vs, tid);

  for (int kt = 0; kt < nt; kt++) {
    __syncthreads();
    if (kt + 1 < nt)
      stage64_4w(kb + (size_t)(kt + 1) * 64 * HD_, vb + (kt + 1) * 64,
                 Ks + ((kt + 1) & 1) * 4096, Vs + ((kt + 1) & 1) * 4096, tid);
    if (kt > last) continue;            // wave-uniform; barriers still honored
    const bf16_t* Kt = Ks + (kt & 1) * 4096;
    const bf16_t* Vc = Vs + (kt & 1) * 4096;

    // QK^T: S^T[k][q], two 32-k subtiles, K summed over 4 d-slices
    floatx16 s0 = {}, s1 = {};
    __builtin_amdgcn_s_setprio(1);
#pragma unroll
    for (int ds = 0; ds < 4; ds++) {
      const int slot = (((ds * 2 + hh) ^ sw7) * 8);
      const short8 k0 = *(const short8*)&Kt[cq * 64 + slot];
      const short8 k1 = *(const short8*)&Kt[(32 + cq) * 64 + slot];
      s0 = __builtin_amdgcn_mfma_f32_32x32x16_bf16(k0, qf[ds], s0, 0, 0, 0);
      s1 = __builtin_amdgcn_mfma_f32_32x32x16_bf16(k1, qf[ds], s1, 0, 0, 0);
    }
    __builtin_amdgcn_s_setprio(0);

    // causal mask on this wave's diag tile
    if (kt == last) {
      const int kbase = kt * 64 + 4 * hh;
#pragma unroll
      for (int r = 0; r < 16; r++) {
        const int kg = kbase + (r & 3) + 8 * (r >> 2);
        s0[r] = (kg <= qg) ? s0[r] : -1e30f;
        s1[r] = (kg + 32 <= qg) ? s1[r] : -1e30f;
      }
    }

    // row max: 3-input groupings -> v_max3_f32 fusion (T17)
    float t[8];
#pragma unroll
    for (int i = 0; i < 8; i++)
      t[i] = fmaxf(fmaxf(fmaxf(s0[i], s0[i + 8]), s1[i]), s1[i + 8]);
    const float v0 = fmaxf(fmaxf(t[0], t[1]), t[2]);
    const float v1 = fmaxf(fmaxf(t[3], t[4]), t[5]);
    const float v2 = fmaxf(fmaxf(t[6], t[7]), v0);
    const float mx = xhalf_max(fmaxf(v1, v2));

    // defer-max (T13): only rescale when max grew by > 8 (exp2 domain)
    if (!__all(mx <= m + 8.0f)) {
      const float mn = fmaxf(m, mx);
      const float a = fexp2(m - mn);
      l *= a;
#pragma unroll
      for (int i = 0; i < 16; i++) { o0[i] *= a; o1[i] *= a; }
      m = mn;
    }

    // P = exp2(S - m), row-sum (per-half partial)
#pragma unroll
    for (int i = 0; i < 16; i++) {
      s0[i] = fexp2(s0[i] - m);
      s1[i] = fexp2(s1[i] - m);
    }
    float u[8];
#pragma unroll
    for (int i = 0; i < 8; i++)
      u[i] = (s0[i] + s0[i + 8]) + (s1[i] + s1[i + 8]);
#pragma unroll
    for (int st = 4; st >= 1; st >>= 1)
#pragma unroll
      for (int i = 0; i < st; i++) u[i] += u[i + st];
    l += u[0];

    // P -> bf16 B-fragments in-register (16 cvt_pk + 8 half-swaps)
    short8 pf[4];
    build_pfrag(s0, pf[0], pf[1]);
    build_pfrag(s1, pf[2], pf[3]);

    // PV: O^T[d][q] += V^T x P^T, two 32-d subtiles, 4 k-slices
    __builtin_amdgcn_s_setprio(1);
#pragma unroll
    for (int ks = 0; ks < 4; ks++) {
      const int slot = (((ks * 2 + hh) ^ sw7) * 8);
      const short8 v0f = *(const short8*)&Vc[cq * 64 + slot];
      const short8 v1f = *(const short8*)&Vc[(32 + cq) * 64 + slot];
      o0 = __builtin_amdgcn_mfma_f32_32x32x16_bf16(v0f, pf[ks], o0, 0, 0, 0);
      o1 = __builtin_amdgcn_mfma_f32_32x32x16_bf16(v1f, pf[ks], o1, 0, 0, 0);
    }
    __builtin_amdgcn_s_setprio(0);
  }

  // epilogue: merge per-half l (permlane), normalize, store
  const float lt = xhalf_sum(l);
  const float li = 1.f / lt;
  bf16_t* obp = O + ((size_t)b * S_ + qg) * (H_ * HD_) + h * HD_ + hh * 4;
#pragma unroll
  for (int rq = 0; rq < 4; rq++) {
    uint2 w0;
    w0.x = pk_bf16(o0[4 * rq] * li, o0[4 * rq + 1] * li);
    w0.y = pk_bf16(o0[4 * rq + 2] * li, o0[4 * rq + 3] * li);
    *(uint2*)(obp + rq * 8) = w0;
    uint2 w1;
    w1.x = pk_bf16(o1[4 * rq] * li, o1[4 * rq + 1] * li);
    w1.y = pk_bf16(o1[4 * rq + 2] * li, o1[4 * rq + 3] * li);
    *(uint2*)(obp + 32 + rq * 8) = w1;
  }
}

extern "C" void kernel_launch(void* const* d_in, const int* in_sizes, int n_in,
                              void* d_out, int out_size, void* d_ws, size_t ws_size,
                              hipStream_t stream) {
  const float* x    = (const float*)d_in[0];
  const float* cs   = (const float*)d_in[1];
  const float* sn   = (const float*)d_in[2];
  const float* wqkv = (const float*)d_in[3];
  const float* wout = (const float*)d_in[4];
  float* out = (float*)d_out;

  char* ws = (char*)d_ws;
  bf16_t*  xb    = (bf16_t*)(ws);                 // 16,777,216 B
  bf16_t*  wqkvb = (bf16_t*)(ws + 16777216);      // 12,582,912 B
  bf16_t*  woutb = (bf16_t*)(ws + 29360128);      //  8,388,608 B
  bf16_t*  qb    = (bf16_t*)(ws + 37748736);      // 16,777,216 B
  bf16_t*  kb    = (bf16_t*)(ws + 54525952);      //  4,194,304 B
  bf16_t*  vtb   = (bf16_t*)(ws + 58720256);      //  4,194,304 B
  bf16_t*  attnb = (bf16_t*)(ws + 62914560);      // 16,777,216 B
  unsigned* tab  = (unsigned*)(ws + 79691776);    //    524,288 B (total ~80 MB)

  prep<<<18944, 256, 0, stream>>>(x, xb, wqkv, wqkvb, wout, woutb, cs, sn, tab);
  gemm_qkv<<<dim3(24, 32), 256, 0, stream>>>(xb, wqkvb, tab, qb, kb, vtb);
  flash_attn<<<1024, 256, 0, stream>>>(qb, kb, vtb, attnb);
  gemm_bt<<<dim3(16, 64), 256, 0, stream>>>(attnb, woutb, out, 4096, 2048, 2048);
}